// Round 1
// baseline (332.305 us; speedup 1.0000x reference)
//
#include <hip/hip_runtime.h>

using u16 = unsigned short;
using u32 = unsigned int;
using s16x8 = __attribute__((ext_vector_type(8))) short;
using bf16x8 = __attribute__((ext_vector_type(8))) __bf16;
using f32x4 = __attribute__((ext_vector_type(4))) float;

__device__ inline u16 f2bf(float f) {
  u32 u = __float_as_uint(f);
  u = (u + 0x7FFFu + ((u >> 16) & 1u)) >> 16;
  return (u16)u;
}

__device__ inline float bf2f(u16 b) { return __uint_as_float(((u32)b) << 16); }

// async global->LDS, 16B per lane; LDS dest = wave-uniform base + lane*16
__device__ inline void load_lds16(const void* g, void* l) {
  __builtin_amdgcn_global_load_lds(
      (const __attribute__((address_space(1))) void*)g,
      (__attribute__((address_space(3))) void*)l, 16, 0, 0);
}

// ---------------------------------------------------------------------------
// Generic cast fp32 -> bf16 (n must be a multiple of 1024)
// ---------------------------------------------------------------------------
__global__ __launch_bounds__(256) void cast_f32_bf16(
    const float* __restrict__ in, u16* __restrict__ out, int n) {
  int i = (blockIdx.x * 256 + threadIdx.x) * 4;
  if (i + 3 < n) {
    float4 f = *(const float4*)(in + i);
    ushort4 o;
    o.x = f2bf(f.x); o.y = f2bf(f.y); o.z = f2bf(f.z); o.w = f2bf(f.w);
    *(ushort4*)(out + i) = o;
  }
}

// ---------------------------------------------------------------------------
// bf16 transpose: in [rows][cols] -> out [cols][rows], per-batch (blockIdx.z)
// ---------------------------------------------------------------------------
__global__ __launch_bounds__(256) void transpose_bf16(
    const u16* __restrict__ in, u16* __restrict__ out, int rows, int cols) {
  __shared__ u16 tile[32][33];
  const size_t boff = (size_t)blockIdx.z * rows * cols;
  const u16* inb = in + boff;
  u16* outb = out + boff;
  const int c0 = blockIdx.x * 32, r0 = blockIdx.y * 32;
  const int tx = threadIdx.x & 31, ty = threadIdx.x >> 5;  // ty: 0..7
#pragma unroll
  for (int j = 0; j < 32; j += 8)
    tile[ty + j][tx] = inb[(size_t)(r0 + ty + j) * cols + c0 + tx];
  __syncthreads();
#pragma unroll
  for (int j = 0; j < 32; j += 8)
    outb[(size_t)(c0 + ty + j) * rows + r0 + tx] = tile[tx][ty + j];
}

// ---------------------------------------------------------------------------
// bf16 GEMM, C[m,n] = sum_k A[m,k]*B[n,k]  (both operands K-contiguous)
// 128x128 tile, BK=32, 4 waves (2x2), 4x4 16x16x32 MFMAs per wave.
// EPI: 0 = +bias, bf16 out; 1 = bf16 out; 2 = fp32 out
// Requires M%128==0, N%128==0, K%32==0.
// ---------------------------------------------------------------------------
template <int EPI>
__global__ __launch_bounds__(256) void gemm_bt(
    const u16* __restrict__ A, const u16* __restrict__ B, void* __restrict__ C,
    const float* __restrict__ bias, int M, int N, int K,
    long sA, long sB, long sC) {
  const int bz = blockIdx.z;
  const u16* Ab = A + (size_t)bz * sA;
  const u16* Bb = B + (size_t)bz * sB;
  const int m0 = blockIdx.y * 128;
  const int n0 = blockIdx.x * 128;
  const int tid = threadIdx.x;
  const int lane = tid & 63;
  const int wave = tid >> 6;
  const int wm = (wave >> 1) * 64;  // wave's 64-row block
  const int wn = (wave & 1) * 64;   // wave's 64-col block

  __shared__ u16 As[128 * 32];
  __shared__ u16 Bs[128 * 32];

  // staging: 8 chunks of 1024B each per tile; wave w stages chunks 2w, 2w+1
  const int sr = lane >> 2;         // row within 16-row chunk
  const int sc = (lane & 3) * 8;    // bf16 col offset (16B granules)
  const int ch0 = wave * 2;

  f32x4 acc[4][4];
#pragma unroll
  for (int i = 0; i < 4; ++i)
#pragma unroll
    for (int j = 0; j < 4; ++j) acc[i][j] = 0.0f;

  const int fr = lane & 15;
  const int fk = (lane >> 4) * 8;

  for (int k0 = 0; k0 < K; k0 += 32) {
#pragma unroll
    for (int it = 0; it < 2; ++it) {
      const int ch = ch0 + it;
      const int row = ch * 16 + sr;
      load_lds16(Ab + (size_t)(m0 + row) * K + k0 + sc, &As[ch * 512]);
      load_lds16(Bb + (size_t)(n0 + row) * K + k0 + sc, &Bs[ch * 512]);
    }
    __syncthreads();
    s16x8 af[4], bfr[4];
#pragma unroll
    for (int i = 0; i < 4; ++i) {
      af[i]  = *(const s16x8*)&As[(wm + i * 16 + fr) * 32 + fk];
      bfr[i] = *(const s16x8*)&Bs[(wn + i * 16 + fr) * 32 + fk];
    }
#pragma unroll
    for (int mi = 0; mi < 4; ++mi)
#pragma unroll
      for (int ni = 0; ni < 4; ++ni)
        acc[mi][ni] = __builtin_amdgcn_mfma_f32_16x16x32_bf16(
            __builtin_bit_cast(bf16x8, af[mi]),
            __builtin_bit_cast(bf16x8, bfr[ni]), acc[mi][ni], 0, 0, 0);
    __syncthreads();
  }

  // C/D layout (verified m89/m91): col = lane&15, row = (lane>>4)*4 + i
  const int er = (lane >> 4) * 4;
  const int ec = lane & 15;
#pragma unroll
  for (int mi = 0; mi < 4; ++mi)
#pragma unroll
    for (int ni = 0; ni < 4; ++ni) {
      const int col = n0 + wn + ni * 16 + ec;
      const float badd = (EPI == 0) ? bias[col] : 0.0f;
#pragma unroll
      for (int i = 0; i < 4; ++i) {
        const int row = m0 + wm + mi * 16 + er + i;
        const float v = acc[mi][ni][i] + badd;
        if (EPI == 2)
          ((float*)C)[(size_t)bz * sC + (size_t)row * N + col] = v;
        else
          ((u16*)C)[(size_t)bz * sC + (size_t)row * N + col] = f2bf(v);
      }
    }
}

// ---------------------------------------------------------------------------
// Row softmax over 2048 bf16 elements, in place. 256 threads, 8 elems/thread.
// Applies `scale` (=1/D) to the raw scores first.
// ---------------------------------------------------------------------------
__global__ __launch_bounds__(256) void softmax_rows(u16* __restrict__ P, float scale) {
  const size_t row = blockIdx.x;
  u16* p = P + row * 2048;
  const int tid = threadIdx.x;
  const int lane = tid & 63;
  const int wave = tid >> 6;

  uint4 u = *(const uint4*)(p + tid * 8);
  float x[8];
  x[0] = bf2f((u16)(u.x & 0xFFFFu)); x[1] = bf2f((u16)(u.x >> 16));
  x[2] = bf2f((u16)(u.y & 0xFFFFu)); x[3] = bf2f((u16)(u.y >> 16));
  x[4] = bf2f((u16)(u.z & 0xFFFFu)); x[5] = bf2f((u16)(u.z >> 16));
  x[6] = bf2f((u16)(u.w & 0xFFFFu)); x[7] = bf2f((u16)(u.w >> 16));

  float mx = -1e30f;
#pragma unroll
  for (int j = 0; j < 8; ++j) {
    x[j] *= scale;
    mx = fmaxf(mx, x[j]);
  }
#pragma unroll
  for (int o = 32; o; o >>= 1) mx = fmaxf(mx, __shfl_xor(mx, o));
  __shared__ float sm[4];
  if (lane == 0) sm[wave] = mx;
  __syncthreads();
  mx = fmaxf(fmaxf(sm[0], sm[1]), fmaxf(sm[2], sm[3]));

  float s = 0.0f;
#pragma unroll
  for (int j = 0; j < 8; ++j) {
    x[j] = __expf(x[j] - mx);
    s += x[j];
  }
#pragma unroll
  for (int o = 32; o; o >>= 1) s += __shfl_xor(s, o);
  __shared__ float ss[4];
  if (lane == 0) ss[wave] = s;
  __syncthreads();
  s = ss[0] + ss[1] + ss[2] + ss[3];
  const float inv = 1.0f / s;

  uint4 o4;
  o4.x = (u32)f2bf(x[0] * inv) | ((u32)f2bf(x[1] * inv) << 16);
  o4.y = (u32)f2bf(x[2] * inv) | ((u32)f2bf(x[3] * inv) << 16);
  o4.z = (u32)f2bf(x[4] * inv) | ((u32)f2bf(x[5] * inv) << 16);
  o4.w = (u32)f2bf(x[6] * inv) | ((u32)f2bf(x[7] * inv) << 16);
  *(uint4*)(p + tid * 8) = o4;
}

// ---------------------------------------------------------------------------
extern "C" void kernel_launch(void* const* d_in, const int* in_sizes, int n_in,
                              void* d_out, int out_size, void* d_ws, size_t ws_size,
                              hipStream_t stream) {
  constexpr int B = 8, S = 2048, D = 512;
  constexpr size_t MS = (size_t)B * S;  // 16384 flattened rows

  const float* x1 = (const float*)d_in[0];
  const float* x2 = (const float*)d_in[1];
  const float* Wq = (const float*)d_in[2];
  const float* bq = (const float*)d_in[3];
  const float* Wk = (const float*)d_in[4];
  const float* bk = (const float*)d_in[5];
  const float* Wv = (const float*)d_in[6];
  const float* bv = (const float*)d_in[7];
  float* out = (float*)d_out;

  // workspace layout (bf16 elements). vT aliases x1b (dead after proj-q).
  u16* x1b = (u16*)d_ws;            // MS*D
  u16* x2b = x1b + MS * D;          // MS*D
  u16* Wqb = x2b + MS * D;          // D*D
  u16* Wkb = Wqb + (size_t)D * D;
  u16* Wvb = Wkb + (size_t)D * D;
  u16* qb  = Wvb + (size_t)D * D;   // MS*D
  u16* kb  = qb + MS * D;           // MS*D
  u16* vb  = kb + MS * D;           // MS*D
  u16* Sc  = vb + MS * D;           // B*S*S  (67 MB)
  u16* vTb = x1b;                   // alias: [B][D][S]

  dim3 blk(256);

  // 1. casts
  cast_f32_bf16<<<(MS * D) / 1024, blk, 0, stream>>>(x1, x1b, MS * D);
  cast_f32_bf16<<<(MS * D) / 1024, blk, 0, stream>>>(x2, x2b, MS * D);
  cast_f32_bf16<<<(D * D) / 1024, blk, 0, stream>>>(Wq, Wqb, D * D);
  cast_f32_bf16<<<(D * D) / 1024, blk, 0, stream>>>(Wk, Wkb, D * D);
  cast_f32_bf16<<<(D * D) / 1024, blk, 0, stream>>>(Wv, Wvb, D * D);

  // 2. projections: [16384,512] = x @ W^T + b   (M=16384, N=512, K=512)
  gemm_bt<0><<<dim3(4, 128, 1), blk, 0, stream>>>(x1b, Wqb, qb, bq, 16384, 512, 512, 0, 0, 0);
  gemm_bt<0><<<dim3(4, 128, 1), blk, 0, stream>>>(x2b, Wkb, kb, bk, 16384, 512, 512, 0, 0, 0);
  gemm_bt<0><<<dim3(4, 128, 1), blk, 0, stream>>>(x2b, Wvb, vb, bv, 16384, 512, 512, 0, 0, 0);

  // 3. v -> v^T per batch: [2048,512] -> [512,2048]
  transpose_bf16<<<dim3(512 / 32, 2048 / 32, B), blk, 0, stream>>>(vb, vTb, 2048, 512);

  // 4. scores (raw, un-scaled): per batch M=2048, N=2048, K=512
  gemm_bt<1><<<dim3(16, 16, B), blk, 0, stream>>>(
      qb, kb, Sc, nullptr, 2048, 2048, 512, (long)S * D, (long)S * D, (long)S * S);

  // 5. softmax rows (applies 1/D scale)
  softmax_rows<<<dim3(B * S), blk, 0, stream>>>(Sc, 1.0f / (float)D);

  // 6. out = P @ V: per batch M=2048, N=512, K=2048; B operand = v^T [D][S]
  gemm_bt<2><<<dim3(4, 16, B), blk, 0, stream>>>(
      Sc, vTb, out, nullptr, 2048, 512, 2048, (long)S * S, (long)D * S, (long)S * D);
}